// Round 1
// baseline (450.711 us; speedup 1.0000x reference)
//
#include <hip/hip_runtime.h>
#include <hip/hip_bf16.h>
#include <cfloat>
#include <cmath>

// Problem constants (fixed by setup_inputs): n=4, L=1024, d=768, h=12, E=32, M=4, R=256
#define N_ 4
#define L_ 1024
#define D_ 768
#define H_ 12
#define E_ 32
#define M_ 4
#define R_ 256
#define OFFSET_ 1

// ---------- dtype-flexible accessors (flag: 1 = fp32, 0 = bf16) ----------
__device__ __forceinline__ float loadF(const void* p, size_t i, int isF32) {
    if (isF32) return ((const float*)p)[i];
    unsigned short u = ((const unsigned short*)p)[i];
    return __uint_as_float(((unsigned int)u) << 16);
}
__device__ __forceinline__ void storeF(void* p, size_t i, float v, int isF32) {
    if (isF32) ((float*)p)[i] = v;
    else ((__hip_bfloat16*)p)[i] = __float2bfloat16(v);
}

// ---------- kernel 0: detect whether float inputs are fp32 or bf16 ----------
// Read 256 uint16 halves of sequence_output (standard normal data).
// If the buffer holds fp32, the even halves are low-mantissa bits = random
// 16-bit patterns -> decoded as bf16 some are huge/NaN. If bf16, all sane.
__global__ void detect_dtype(const unsigned short* seq_u16, int* flag) {
    int tid = threadIdx.x;
    bool bad = false;
    for (int i = tid; i < 256; i += 64) {
        float v = __uint_as_float(((unsigned int)seq_u16[i]) << 16);
        if (!(fabsf(v) <= 1000.0f)) bad = true;   // catches huge + NaN
    }
    unsigned long long m = __ballot(bad);
    if (tid == 0) *flag = (m != 0ULL) ? 1 : 0;
}

// ---------- kernel 1: per (doc, entity): e_emb (logsumexp) + e_att ----------
__global__ void k1_entity(const void* seq, const void* att, const int* mpos,
                          const void* mmask, const int* flag,
                          float* e_emb, float* e_att) {
    const int isF32 = *flag;
    const int b = blockIdx.x;          // n*E
    const int doc = b / E_, e = b % E_;
    const int tid = threadIdx.x;

    __shared__ int   spos[M_];
    __shared__ float smask[M_];
    if (tid < M_) {
        spos[tid]  = mpos[(doc * E_ + e) * M_ + tid] + OFFSET_;
        smask[tid] = loadF(mmask, (size_t)(doc * E_ + e) * M_ + tid, isF32);
    }
    __syncthreads();

    float cnt = smask[0] + smask[1] + smask[2] + smask[3];
    cnt = fmaxf(cnt, 1.0f);
    const float inv_cnt = 1.0f / cnt;

    // e_emb: masked logsumexp over M mentions, per dim
    for (int j = tid; j < D_; j += blockDim.x) {
        float v[M_];
        #pragma unroll
        for (int m = 0; m < M_; m++) {
            float x = loadF(seq, (size_t)doc * L_ * D_ + (size_t)spos[m] * D_ + j, isF32);
            v[m] = (smask[m] > 0.0f) ? x : -FLT_MAX;
        }
        float mx = fmaxf(fmaxf(v[0], v[1]), fmaxf(v[2], v[3]));
        float s = 0.0f;
        #pragma unroll
        for (int m = 0; m < M_; m++) s += expf(v[m] - mx);
        e_emb[(size_t)(doc * E_ + e) * D_ + j] = mx + logf(s);
    }

    // e_att[e][head][l] = sum_m mask[m] * att[doc][head][pos[m]][l] / cnt
    for (int idx = tid; idx < H_ * L_; idx += blockDim.x) {
        int head = idx >> 10;          // idx / L_
        int l    = idx & (L_ - 1);     // idx % L_
        float s = 0.0f;
        #pragma unroll
        for (int m = 0; m < M_; m++) {
            size_t off = ((size_t)(doc * H_ + head) * L_ + (size_t)spos[m]) * L_ + l;
            s += smask[m] * loadF(att, off, isF32);
        }
        e_att[((size_t)(doc * E_ + e) * H_ + head) * L_ + l] = s * inv_cnt;
    }
}

// ---------- kernel 2: per (doc, r): write hs/ts, compute normalized ht_att ----------
__global__ void k2_pairs(const int* hts, const int* flag,
                         const float* e_emb, const float* e_att,
                         float* ht_att, void* out) {
    const int isF32 = *flag;
    const int b = blockIdx.x;          // n*R
    const int doc = b / R_, r = b % R_;
    const int tid = threadIdx.x;

    const int hi = hts[(size_t)(doc * R_ + r) * 2 + 0];
    const int ti = hts[(size_t)(doc * R_ + r) * 2 + 1];

    // hs / ts gather -> outputs 0 and 1
    for (int j = tid; j < D_; j += blockDim.x) {
        float hv = e_emb[(size_t)(doc * E_ + hi) * D_ + j];
        float tv = e_emb[(size_t)(doc * E_ + ti) * D_ + j];
        storeF(out, (size_t)(doc * R_ + r) * D_ + j, hv, isF32);
        storeF(out, (size_t)N_ * R_ * D_ + (size_t)(doc * R_ + r) * D_ + j, tv, isF32);
    }

    // ht_att[l] = mean_heads(h_att * t_att); then normalize over L
    const float* ha = e_att + (size_t)(doc * E_ + hi) * H_ * L_;
    const float* ta = e_att + (size_t)(doc * E_ + ti) * H_ * L_;

    float vals[L_ / 256];
    float psum = 0.0f;
    #pragma unroll
    for (int i = 0; i < L_ / 256; i++) {
        int l = tid + i * 256;
        float s = 0.0f;
        #pragma unroll
        for (int head = 0; head < H_; head++)
            s += ha[(size_t)head * L_ + l] * ta[(size_t)head * L_ + l];
        s *= (1.0f / H_);
        vals[i] = s;
        psum += s;
    }

    // block reduction of psum over 256 threads (4 waves)
    __shared__ float swave[4];
    __shared__ float stotal;
    float p = psum;
    #pragma unroll
    for (int off = 32; off > 0; off >>= 1) p += __shfl_down(p, off, 64);
    int wid = tid >> 6, lane = tid & 63;
    if (lane == 0) swave[wid] = p;
    __syncthreads();
    if (tid == 0) stotal = swave[0] + swave[1] + swave[2] + swave[3];
    __syncthreads();
    const float norm = 1.0f / (stotal + 1e-5f);

    #pragma unroll
    for (int i = 0; i < L_ / 256; i++) {
        int l = tid + i * 256;
        ht_att[(size_t)(doc * R_ + r) * L_ + l] = vals[i] * norm;
    }
}

// ---------- kernel 3: rs = ht_att (R x L) @ seq (L x D), per doc ----------
#define BM 32
#define BN 64
#define BK 64
__global__ void k3_rs(const void* seq, const int* flag, const float* ht_att, void* out) {
    const int isF32 = *flag;
    const int doc = blockIdx.z;
    const int rb = blockIdx.y * BM;
    const int jb = blockIdx.x * BN;
    const int tid = threadIdx.x;       // 256
    const int tr = tid >> 4;           // 0..15 -> 2 rows each
    const int tc = tid & 15;           // 0..15 -> 4 cols each

    __shared__ float As[BM][BK + 1];   // +1 pad: break 4-way bank conflict on a-broadcast
    __shared__ float Bs[BK][BN];

    float acc[2][4] = {{0.f, 0.f, 0.f, 0.f}, {0.f, 0.f, 0.f, 0.f}};

    for (int k0 = 0; k0 < L_; k0 += BK) {
        for (int i = tid; i < BM * BK; i += 256) {
            int row = i >> 6, kk = i & 63;
            As[row][kk] = ht_att[(size_t)(doc * R_ + rb + row) * L_ + k0 + kk];
        }
        for (int i = tid; i < BK * BN; i += 256) {
            int kk = i >> 6, col = i & 63;
            Bs[kk][col] = loadF(seq, (size_t)doc * L_ * D_ + (size_t)(k0 + kk) * D_ + jb + col, isF32);
        }
        __syncthreads();

        #pragma unroll 8
        for (int kk = 0; kk < BK; kk++) {
            float a0 = As[tr * 2 + 0][kk];
            float a1 = As[tr * 2 + 1][kk];
            float b0 = Bs[kk][tc * 4 + 0];
            float b1 = Bs[kk][tc * 4 + 1];
            float b2 = Bs[kk][tc * 4 + 2];
            float b3 = Bs[kk][tc * 4 + 3];
            acc[0][0] += a0 * b0; acc[0][1] += a0 * b1; acc[0][2] += a0 * b2; acc[0][3] += a0 * b3;
            acc[1][0] += a1 * b0; acc[1][1] += a1 * b1; acc[1][2] += a1 * b2; acc[1][3] += a1 * b3;
        }
        __syncthreads();
    }

    const size_t rs_base = (size_t)2 * N_ * R_ * D_;
    #pragma unroll
    for (int rr = 0; rr < 2; rr++) {
        #pragma unroll
        for (int cc = 0; cc < 4; cc++) {
            int r = rb + tr * 2 + rr;
            int j = jb + tc * 4 + cc;
            storeF(out, rs_base + (size_t)(doc * R_ + r) * D_ + j, acc[rr][cc], isF32);
        }
    }
}

extern "C" void kernel_launch(void* const* d_in, const int* in_sizes, int n_in,
                              void* d_out, int out_size, void* d_ws, size_t ws_size,
                              hipStream_t stream) {
    const void* seq   = d_in[0];                  // (n, L, d) float-ish
    const void* att   = d_in[1];                  // (n, h, L, L) float-ish
    const int*  mpos  = (const int*)d_in[2];      // (n, E, M) int32
    const void* mmask = d_in[3];                  // (n, E, M) float-ish
    const int*  hts   = (const int*)d_in[4];      // (n, R, 2) int32

    // workspace layout (all fp32 intermediates)
    int*   flag   = (int*)d_ws;
    float* e_emb  = (float*)((char*)d_ws + 256);            // n*E*d
    float* e_att  = e_emb + (size_t)N_ * E_ * D_;           // n*E*h*L
    float* ht_att = e_att + (size_t)N_ * E_ * H_ * L_;      // n*R*L

    detect_dtype<<<1, 64, 0, stream>>>((const unsigned short*)seq, flag);
    k1_entity<<<N_ * E_, 256, 0, stream>>>(seq, att, mpos, mmask, flag, e_emb, e_att);
    k2_pairs<<<N_ * R_, 256, 0, stream>>>(hts, flag, e_emb, e_att, ht_att, d_out);
    dim3 g3(D_ / BN, R_ / BM, N_);
    k3_rs<<<g3, 256, 0, stream>>>(seq, flag, ht_att, d_out);
}

// Round 3
// 272.031 us; speedup vs baseline: 1.6568x; 1.6568x over previous
//
#include <hip/hip_runtime.h>
#include <cfloat>
#include <cmath>

// Constants fixed by setup_inputs: n=4, L=1024, d=768, h=12, E=32, M=4, R=256
#define N_ 4
#define L_ 1024
#define D_ 768
#define H_ 12
#define E_ 32
#define M_ 4
#define R_ 256

// Confirmed round 1 (k3_rs WRITE_SIZE == 3072 KB == N*R*D*4B): inputs & output are FP32.
// Intermediates seqT / e_att / ht are bf16 (feeds MFMA); e_emb stays fp32 (hs/ts exact).
typedef __attribute__((ext_vector_type(8))) short bf16x8;   // MFMA A/B frag (4 VGPR)
typedef __attribute__((ext_vector_type(4))) float f32x4;    // MFMA C/D frag

__device__ __forceinline__ ushort f2bf(float f) {
    unsigned u = __float_as_uint(f);
    return (ushort)((u + 0x7fffu + ((u >> 16) & 1u)) >> 16);   // RNE
}
__device__ __forceinline__ float bf2f(ushort u) { return __uint_as_float(((unsigned)u) << 16); }

// ---------------- k0: seqT[doc][d][l] = bf16(seq[doc][l][d])  (swizzled-LDS transpose) ---
// tile 64(l) x 64(d); slot(l,d) = (d + (l&56)) & 63 -> conflict-free on both phases
__global__ void k0_transpose(const float* __restrict__ seq, ushort* __restrict__ seqT) {
    const int doc = blockIdx.z;
    const int l0 = blockIdx.x * 64;
    const int d0 = blockIdx.y * 64;
    const int t = threadIdx.x;                 // 256
    __shared__ ushort tile[64 * 64];
    #pragma unroll
    for (int i = 0; i < 2; i++) {
        int idx = t + i * 256;                 // 0..511
        int row = idx >> 3;                    // l-local
        int c8  = (idx & 7) << 3;              // d-local chunk start
        const float* src = seq + ((size_t)doc * L_ + (l0 + row)) * D_ + d0 + c8;
        float4 v0 = *(const float4*)(src);
        float4 v1 = *(const float4*)(src + 4);
        ushort tmp[8] = { f2bf(v0.x), f2bf(v0.y), f2bf(v0.z), f2bf(v0.w),
                          f2bf(v1.x), f2bf(v1.y), f2bf(v1.z), f2bf(v1.w) };
        int slot = (c8 + (row & 56)) & 63;     // multiple of 8, chunk never wraps
        *(uint4*)(tile + row * 64 + slot) = *(const uint4*)tmp;
    }
    __syncthreads();
    #pragma unroll
    for (int i = 0; i < 2; i++) {
        int idx = t + i * 256;
        int drow = idx >> 3;                   // d-local
        int l8 = (idx & 7) << 3;               // l-local chunk
        int slot = (drow + l8) & 63;           // == (drow + ((l8+j)&56)) & 63 for j<8
        ushort tmp[8];
        #pragma unroll
        for (int j = 0; j < 8; j++) tmp[j] = tile[(l8 + j) * 64 + slot];
        *(uint4*)(seqT + ((size_t)doc * D_ + (d0 + drow)) * L_ + l0 + l8) = *(const uint4*)tmp;
    }
}

// ---------------- k1: per (doc,entity,head): e_att (bf16); head==0 also e_emb (fp32 lse) -
__global__ void k1_entity(const float* __restrict__ seq, const float* __restrict__ att,
                          const int* __restrict__ mpos, const float* __restrict__ mmask,
                          float* __restrict__ e_emb, ushort* __restrict__ e_att) {
    const int be = blockIdx.x;                 // doc*E + e
    const int head = blockIdx.y;
    const int doc = be >> 5;
    const int t = threadIdx.x;                 // 128

    __shared__ int   spos[M_];
    __shared__ float smask[M_];
    if (t < M_) {
        spos[t]  = mpos[be * M_ + t] + 1;      // OFFSET
        smask[t] = mmask[be * M_ + t];
    }
    __syncthreads();
    const float cnt = fmaxf(smask[0] + smask[1] + smask[2] + smask[3], 1.0f);
    const float inv_cnt = 1.0f / cnt;

    // e_att[be][head][l] = sum_m mask*att[doc][head][pos_m][l] / cnt  -> bf16
    {
        const int l8 = t << 3;
        float s[8] = {0, 0, 0, 0, 0, 0, 0, 0};
        #pragma unroll
        for (int m = 0; m < M_; m++) {
            const float* src = att + (((size_t)doc * H_ + head) * L_ + spos[m]) * L_ + l8;
            float4 r0 = *(const float4*)(src);
            float4 r1 = *(const float4*)(src + 4);
            const float w = smask[m];
            s[0] += w * r0.x; s[1] += w * r0.y; s[2] += w * r0.z; s[3] += w * r0.w;
            s[4] += w * r1.x; s[5] += w * r1.y; s[6] += w * r1.z; s[7] += w * r1.w;
        }
        ushort o[8];
        #pragma unroll
        for (int j = 0; j < 8; j++) o[j] = f2bf(s[j] * inv_cnt);
        *(uint4*)(e_att + ((size_t)be * H_ + head) * L_ + l8) = *(const uint4*)o;
    }

    // e_emb: masked logsumexp over M mentions, fp32 (once, head==0)
    if (head == 0 && t < 96) {
        const int j8 = t << 3;
        float v[M_][8];
        #pragma unroll
        for (int m = 0; m < M_; m++) {
            const float* src = seq + ((size_t)doc * L_ + spos[m]) * D_ + j8;
            float4 r0 = *(const float4*)(src);
            float4 r1 = *(const float4*)(src + 4);
            v[m][0] = r0.x; v[m][1] = r0.y; v[m][2] = r0.z; v[m][3] = r0.w;
            v[m][4] = r1.x; v[m][5] = r1.y; v[m][6] = r1.z; v[m][7] = r1.w;
        }
        float o[8];
        #pragma unroll
        for (int j = 0; j < 8; j++) {
            float x[M_];
            #pragma unroll
            for (int m = 0; m < M_; m++) x[m] = (smask[m] > 0.0f) ? v[m][j] : -FLT_MAX;
            float mx = fmaxf(fmaxf(x[0], x[1]), fmaxf(x[2], x[3]));
            float s = 0.0f;
            #pragma unroll
            for (int m = 0; m < M_; m++) s += expf(x[m] - mx);
            o[j] = mx + logf(s);
        }
        float* dst = e_emb + (size_t)be * D_ + j8;
        *(float4*)(dst)     = make_float4(o[0], o[1], o[2], o[3]);
        *(float4*)(dst + 4) = make_float4(o[4], o[5], o[6], o[7]);
    }
}

// ---------------- k2: per pair: hs/ts (fp32 copies), ht_att (normalized bf16) ------------
__global__ void k2_pairs(const int* __restrict__ hts, const float* __restrict__ e_emb,
                         const ushort* __restrict__ e_att, ushort* __restrict__ ht_att,
                         float* __restrict__ out) {
    const int b = blockIdx.x;                  // doc*R + r
    const int doc = b >> 8;
    const int t = threadIdx.x;                 // 256
    const int hi = hts[b * 2 + 0];
    const int ti = hts[b * 2 + 1];

    // hs / ts: exact fp32 copies of e_emb rows
    if (t < 192) {
        const int j4 = t << 2;                 // 0..764
        float4 hv = *(const float4*)(e_emb + (size_t)(doc * E_ + hi) * D_ + j4);
        float4 tv = *(const float4*)(e_emb + (size_t)(doc * E_ + ti) * D_ + j4);
        *(float4*)(out + (size_t)b * D_ + j4) = hv;
        *(float4*)(out + (size_t)N_ * R_ * D_ + (size_t)b * D_ + j4) = tv;
    }

    // ht_att[l] = mean_h(ha*ta), normalized over L -> bf16
    const ushort* ha = e_att + (size_t)(doc * E_ + hi) * H_ * L_;
    const ushort* ta = e_att + (size_t)(doc * E_ + ti) * H_ * L_;
    const int l4 = t << 2;
    float s[4] = {0, 0, 0, 0};
    #pragma unroll
    for (int head = 0; head < H_; head++) {
        union { uint2 v; ushort u[4]; } x, y;
        x.v = *(const uint2*)(ha + head * L_ + l4);
        y.v = *(const uint2*)(ta + head * L_ + l4);
        #pragma unroll
        for (int j = 0; j < 4; j++) s[j] += bf2f(x.u[j]) * bf2f(y.u[j]);
    }
    #pragma unroll
    for (int j = 0; j < 4; j++) s[j] *= (1.0f / H_);
    float p = s[0] + s[1] + s[2] + s[3];
    #pragma unroll
    for (int off = 32; off > 0; off >>= 1) p += __shfl_down(p, off, 64);
    __shared__ float swave[4];
    if ((t & 63) == 0) swave[t >> 6] = p;
    __syncthreads();
    const float total = swave[0] + swave[1] + swave[2] + swave[3];
    const float norm = 1.0f / (total + 1e-5f);
    ushort o[4];
    #pragma unroll
    for (int j = 0; j < 4; j++) o[j] = f2bf(s[j] * norm);
    *(uint2*)(ht_att + (size_t)b * L_ + l4) = *(const uint2*)o;
}

// ---------------- k3: rs[r][d] via MFMA: D[d][r] = sum_l seqT[d][l] * ht[r][l] -----------
// one wave per block; tile 32(d) x 32(r); frags straight from global; fp32 output
__global__ void k3_rs(const ushort* __restrict__ seqT, const ushort* __restrict__ ht,
                      float* __restrict__ out_rs) {
    const int doc = blockIdx.z;
    const int d0 = blockIdx.x * 32;
    const int r0 = blockIdx.y * 32;
    const int lane = threadIdx.x;              // 64
    const int l15 = lane & 15;
    const int quad = lane >> 4;

    // A[m=lane&15][k=quad*8+j] layout; same shape for B^T rows
    const ushort* Ab = seqT + ((size_t)doc * D_ + d0 + l15) * L_ + quad * 8;
    const ushort* Bb = ht   + ((size_t)doc * R_ + r0 + l15) * L_ + quad * 8;

    bf16x8 a0 = *(const bf16x8*)(Ab);
    bf16x8 a1 = *(const bf16x8*)(Ab + 16 * L_);
    bf16x8 b0 = *(const bf16x8*)(Bb);
    bf16x8 b1 = *(const bf16x8*)(Bb + 16 * L_);
    f32x4 c00 = {0, 0, 0, 0}, c01 = {0, 0, 0, 0}, c10 = {0, 0, 0, 0}, c11 = {0, 0, 0, 0};

    for (int k = 0; k < L_; k += 32) {
        bf16x8 na0 = a0, na1 = a1, nb0 = b0, nb1 = b1;
        if (k + 32 < L_) {
            na0 = *(const bf16x8*)(Ab + k + 32);
            na1 = *(const bf16x8*)(Ab + k + 32 + 16 * L_);
            nb0 = *(const bf16x8*)(Bb + k + 32);
            nb1 = *(const bf16x8*)(Bb + k + 32 + 16 * L_);
        }
        c00 = __builtin_amdgcn_mfma_f32_16x16x32_bf16(a0, b0, c00, 0, 0, 0);
        c01 = __builtin_amdgcn_mfma_f32_16x16x32_bf16(a0, b1, c01, 0, 0, 0);
        c10 = __builtin_amdgcn_mfma_f32_16x16x32_bf16(a1, b0, c10, 0, 0, 0);
        c11 = __builtin_amdgcn_mfma_f32_16x16x32_bf16(a1, b1, c11, 0, 0, 0);
        a0 = na0; a1 = na1; b0 = nb0; b1 = nb1;
    }

    // C/D layout: col(=r) = lane&15, row(=d) = quad*4 + reg
    f32x4 cc[2][2] = {{c00, c01}, {c10, c11}};
    #pragma unroll
    for (int di = 0; di < 2; di++) {
        #pragma unroll
        for (int ri = 0; ri < 2; ri++) {
            const int r = r0 + ri * 16 + l15;
            const int d = d0 + di * 16 + quad * 4;
            *(f32x4*)(out_rs + ((size_t)doc * R_ + r) * D_ + d) = cc[di][ri];
        }
    }
}

extern "C" void kernel_launch(void* const* d_in, const int* in_sizes, int n_in,
                              void* d_out, int out_size, void* d_ws, size_t ws_size,
                              hipStream_t stream) {
    const float* seq   = (const float*)d_in[0];   // (n,L,d) fp32
    const float* att   = (const float*)d_in[1];   // (n,h,L,L) fp32
    const int*   mpos  = (const int*)d_in[2];     // (n,E,M) int32
    const float* mmask = (const float*)d_in[3];   // (n,E,M) fp32
    const int*   hts   = (const int*)d_in[4];     // (n,R,2) int32
    float* out = (float*)d_out;                   // 3*(n*R)*d fp32

    // workspace: e_emb fp32, then bf16 intermediates (~11.4 MB total)
    float*  e_emb = (float*)d_ws;                                    // n*E*D
    ushort* seqT  = (ushort*)(e_emb + (size_t)N_ * E_ * D_);         // n*D*L
    ushort* e_att = seqT  + (size_t)N_ * D_ * L_;                    // n*E*H*L
    ushort* ht    = e_att + (size_t)N_ * E_ * H_ * L_;               // n*R*L

    dim3 g0(L_ / 64, D_ / 64, N_);
    k0_transpose<<<g0, 256, 0, stream>>>(seq, seqT);
    dim3 g1(N_ * E_, H_);
    k1_entity<<<g1, 128, 0, stream>>>(seq, att, mpos, mmask, e_emb, e_att);
    k2_pairs<<<N_ * R_, 256, 0, stream>>>(hts, e_emb, e_att, ht, out);
    dim3 g3(D_ / 32, R_ / 32, N_);
    k3_rs<<<g3, 64, 0, stream>>>(seqT, ht, out + (size_t)2 * N_ * R_ * D_);
}

// Round 4
// 269.422 us; speedup vs baseline: 1.6729x; 1.0097x over previous
//
#include <hip/hip_runtime.h>
#include <cfloat>
#include <cmath>

// Constants fixed by setup_inputs: n=4, L=1024, d=768, h=12, E=32, M=4, R=256
#define N_ 4
#define L_ 1024
#define D_ 768
#define H_ 12
#define E_ 32
#define M_ 4
#define R_ 256

// Inputs & output FP32 (confirmed R1: k3 WRITE_SIZE == N*R*D*4B).
// Intermediates seqT / e_att / ht are bf16 (feed MFMA); e_emb fp32 (hs/ts exact).
typedef __attribute__((ext_vector_type(8))) short bf16x8;   // MFMA A/B frag
typedef __attribute__((ext_vector_type(4))) float f32x4;    // MFMA C/D frag

__device__ __forceinline__ ushort f2bf(float f) {
    unsigned u = __float_as_uint(f);
    return (ushort)((u + 0x7fffu + ((u >> 16) & 1u)) >> 16);   // RNE
}
__device__ __forceinline__ float bf2f(ushort u) { return __uint_as_float(((unsigned)u) << 16); }

// ---------------- k01: fused (independent) transpose-role + entity-role ------------------
// blocks [0,768): seqT[doc][d][l] = bf16(seq[doc][l][d]), 64x64 swizzled-LDS tile
// blocks [768, 768+1536): per (doc,entity,head) e_att (bf16); head==0 lanes also e_emb lse
__global__ __launch_bounds__(256) void k01(const float* __restrict__ seq,
                                           const float* __restrict__ att,
                                           const int* __restrict__ mpos,
                                           const float* __restrict__ mmask,
                                           ushort* __restrict__ seqT,
                                           float* __restrict__ e_emb,
                                           ushort* __restrict__ e_att) {
    const int b = blockIdx.x;
    const int t = threadIdx.x;                 // 256
    __shared__ ushort tile[64 * 64];           // 8 KB (transpose role); entity uses 16 B

    if (b < 768) {
        // ---- transpose role: grid factors 16(l-tile) x 12(d-tile) x 4(doc)
        const int lt = b & 15, dt = (b >> 4) % 12, doc = b / 192;
        const int l0 = lt * 64, d0 = dt * 64;
        #pragma unroll
        for (int i = 0; i < 2; i++) {
            int idx = t + i * 256;             // 0..511
            int row = idx >> 3;                // l-local
            int c8  = (idx & 7) << 3;          // d-local chunk start
            const float* src = seq + ((size_t)doc * L_ + (l0 + row)) * D_ + d0 + c8;
            float4 v0 = *(const float4*)(src);
            float4 v1 = *(const float4*)(src + 4);
            ushort tmp[8] = { f2bf(v0.x), f2bf(v0.y), f2bf(v0.z), f2bf(v0.w),
                              f2bf(v1.x), f2bf(v1.y), f2bf(v1.z), f2bf(v1.w) };
            int slot = (c8 + (row & 56)) & 63; // swizzle; chunk never wraps
            *(uint4*)(tile + row * 64 + slot) = *(const uint4*)tmp;
        }
        __syncthreads();
        #pragma unroll
        for (int i = 0; i < 2; i++) {
            int idx = t + i * 256;
            int drow = idx >> 3;               // d-local
            int l8 = (idx & 7) << 3;           // l-local chunk
            int slot = (drow + l8) & 63;
            ushort tmp[8];
            #pragma unroll
            for (int j = 0; j < 8; j++) tmp[j] = tile[(l8 + j) * 64 + slot];
            *(uint4*)(seqT + ((size_t)doc * D_ + (d0 + drow)) * L_ + l0 + l8) = *(const uint4*)tmp;
        }
        return;
    }

    // ---- entity role: b2 in [0,1536) = be*H + head
    const int b2 = b - 768;
    const int head = b2 % H_;
    const int be = b2 / H_;                    // doc*E + e
    const int doc = be >> 5;

    __shared__ int   spos[M_];
    __shared__ float smask[M_];
    if (t < M_) {
        spos[t]  = mpos[be * M_ + t] + 1;      // OFFSET
        smask[t] = mmask[be * M_ + t];
    }
    __syncthreads();
    const float cnt = fmaxf(smask[0] + smask[1] + smask[2] + smask[3], 1.0f);
    const float inv_cnt = 1.0f / cnt;

    // e_att: all 256 threads, 4 floats each (float4, 16B/lane perfectly coalesced)
    {
        const int l4 = t << 2;
        float s0 = 0, s1 = 0, s2 = 0, s3 = 0;
        #pragma unroll
        for (int m = 0; m < M_; m++) {
            float4 r = *(const float4*)(att + (((size_t)doc * H_ + head) * L_ + spos[m]) * L_ + l4);
            const float w = smask[m];
            s0 += w * r.x; s1 += w * r.y; s2 += w * r.z; s3 += w * r.w;
        }
        ushort o[4] = { f2bf(s0 * inv_cnt), f2bf(s1 * inv_cnt),
                        f2bf(s2 * inv_cnt), f2bf(s3 * inv_cnt) };
        *(uint2*)(e_att + ((size_t)be * H_ + head) * L_ + l4) = *(const uint2*)o;
    }

    // e_emb lse (fp32), once per entity, concurrent with e_att above
    if (head == 0 && t < 96) {
        const int j8 = t << 3;
        float v[M_][8];
        #pragma unroll
        for (int m = 0; m < M_; m++) {
            const float* src = seq + ((size_t)doc * L_ + spos[m]) * D_ + j8;
            float4 r0 = *(const float4*)(src);
            float4 r1 = *(const float4*)(src + 4);
            v[m][0] = r0.x; v[m][1] = r0.y; v[m][2] = r0.z; v[m][3] = r0.w;
            v[m][4] = r1.x; v[m][5] = r1.y; v[m][6] = r1.z; v[m][7] = r1.w;
        }
        float o[8];
        #pragma unroll
        for (int j = 0; j < 8; j++) {
            float x[M_];
            #pragma unroll
            for (int m = 0; m < M_; m++) x[m] = (smask[m] > 0.0f) ? v[m][j] : -FLT_MAX;
            float mx = fmaxf(fmaxf(x[0], x[1]), fmaxf(x[2], x[3]));
            float s = 0.0f;
            #pragma unroll
            for (int m = 0; m < M_; m++) s += expf(x[m] - mx);
            o[j] = mx + logf(s);
        }
        float* dst = e_emb + (size_t)be * D_ + j8;
        *(float4*)(dst)     = make_float4(o[0], o[1], o[2], o[3]);
        *(float4*)(dst + 4) = make_float4(o[4], o[5], o[6], o[7]);
    }
}

// ---------------- k2: per pair: hs/ts (fp32 copies), ht_att (normalized bf16) ------------
__global__ __launch_bounds__(256) void k2_pairs(const int* __restrict__ hts,
                                                const float* __restrict__ e_emb,
                                                const ushort* __restrict__ e_att,
                                                ushort* __restrict__ ht_att,
                                                float* __restrict__ out) {
    const int b = blockIdx.x;                  // doc*R + r
    const int doc = b >> 8;
    const int t = threadIdx.x;                 // 256
    const int hi = hts[b * 2 + 0];
    const int ti = hts[b * 2 + 1];

    if (t < 192) {                             // hs / ts: exact fp32 copies
        const int j4 = t << 2;
        float4 hv = *(const float4*)(e_emb + (size_t)(doc * E_ + hi) * D_ + j4);
        float4 tv = *(const float4*)(e_emb + (size_t)(doc * E_ + ti) * D_ + j4);
        *(float4*)(out + (size_t)b * D_ + j4) = hv;
        *(float4*)(out + (size_t)N_ * R_ * D_ + (size_t)b * D_ + j4) = tv;
    }

    const ushort* ha = e_att + (size_t)(doc * E_ + hi) * H_ * L_;
    const ushort* ta = e_att + (size_t)(doc * E_ + ti) * H_ * L_;
    const int l4 = t << 2;
    float s[4] = {0, 0, 0, 0};
    #pragma unroll
    for (int head = 0; head < H_; head++) {
        union { uint2 v; ushort u[4]; } x, y;
        x.v = *(const uint2*)(ha + head * L_ + l4);
        y.v = *(const uint2*)(ta + head * L_ + l4);
        #pragma unroll
        for (int j = 0; j < 4; j++) s[j] += bf2f(x.u[j]) * bf2f(y.u[j]);
    }
    #pragma unroll
    for (int j = 0; j < 4; j++) s[j] *= (1.0f / H_);
    float p = s[0] + s[1] + s[2] + s[3];
    #pragma unroll
    for (int off = 32; off > 0; off >>= 1) p += __shfl_down(p, off, 64);
    __shared__ float swave[4];
    if ((t & 63) == 0) swave[t >> 6] = p;
    __syncthreads();
    const float total = swave[0] + swave[1] + swave[2] + swave[3];
    const float norm = 1.0f / (total + 1e-5f);
    ushort o[4];
    #pragma unroll
    for (int j = 0; j < 4; j++) o[j] = f2bf(s[j] * norm);
    *(uint2*)(ht_att + (size_t)b * L_ + l4) = *(const uint2*)o;
}

// ---------------- k3: rs via MFMA: D[d][r] = sum_l seqT[d][l] * ht[r][l] -----------------
__global__ void k3_rs(const ushort* __restrict__ seqT, const ushort* __restrict__ ht,
                      float* __restrict__ out_rs) {
    const int doc = blockIdx.z;
    const int d0 = blockIdx.x * 32;
    const int r0 = blockIdx.y * 32;
    const int lane = threadIdx.x;              // 64
    const int l15 = lane & 15;
    const int quad = lane >> 4;

    const ushort* Ab = seqT + ((size_t)doc * D_ + d0 + l15) * L_ + quad * 8;
    const ushort* Bb = ht   + ((size_t)doc * R_ + r0 + l15) * L_ + quad * 8;

    bf16x8 a0 = *(const bf16x8*)(Ab);
    bf16x8 a1 = *(const bf16x8*)(Ab + 16 * L_);
    bf16x8 b0 = *(const bf16x8*)(Bb);
    bf16x8 b1 = *(const bf16x8*)(Bb + 16 * L_);
    f32x4 c00 = {0, 0, 0, 0}, c01 = {0, 0, 0, 0}, c10 = {0, 0, 0, 0}, c11 = {0, 0, 0, 0};

    for (int k = 0; k < L_; k += 32) {
        bf16x8 na0 = a0, na1 = a1, nb0 = b0, nb1 = b1;
        if (k + 32 < L_) {
            na0 = *(const bf16x8*)(Ab + k + 32);
            na1 = *(const bf16x8*)(Ab + k + 32 + 16 * L_);
            nb0 = *(const bf16x8*)(Bb + k + 32);
            nb1 = *(const bf16x8*)(Bb + k + 32 + 16 * L_);
        }
        c00 = __builtin_amdgcn_mfma_f32_16x16x32_bf16(a0, b0, c00, 0, 0, 0);
        c01 = __builtin_amdgcn_mfma_f32_16x16x32_bf16(a0, b1, c01, 0, 0, 0);
        c10 = __builtin_amdgcn_mfma_f32_16x16x32_bf16(a1, b0, c10, 0, 0, 0);
        c11 = __builtin_amdgcn_mfma_f32_16x16x32_bf16(a1, b1, c11, 0, 0, 0);
        a0 = na0; a1 = na1; b0 = nb0; b1 = nb1;
    }

    // C/D layout: col(=r) = lane&15, row(=d) = quad*4 + reg
    f32x4 cc[2][2] = {{c00, c01}, {c10, c11}};
    #pragma unroll
    for (int di = 0; di < 2; di++) {
        #pragma unroll
        for (int ri = 0; ri < 2; ri++) {
            const int r = r0 + ri * 16 + l15;
            const int d = d0 + di * 16 + quad * 4;
            *(f32x4*)(out_rs + ((size_t)doc * R_ + r) * D_ + d) = cc[di][ri];
        }
    }
}

extern "C" void kernel_launch(void* const* d_in, const int* in_sizes, int n_in,
                              void* d_out, int out_size, void* d_ws, size_t ws_size,
                              hipStream_t stream) {
    const float* seq   = (const float*)d_in[0];   // (n,L,d) fp32
    const float* att   = (const float*)d_in[1];   // (n,h,L,L) fp32
    const int*   mpos  = (const int*)d_in[2];     // (n,E,M) int32
    const float* mmask = (const float*)d_in[3];   // (n,E,M) fp32
    const int*   hts   = (const int*)d_in[4];     // (n,R,2) int32
    float* out = (float*)d_out;                   // 3*(n*R)*d fp32

    float*  e_emb = (float*)d_ws;                                    // n*E*D fp32
    ushort* seqT  = (ushort*)(e_emb + (size_t)N_ * E_ * D_);         // n*D*L bf16
    ushort* e_att = seqT  + (size_t)N_ * D_ * L_;                    // n*E*H*L bf16
    ushort* ht    = e_att + (size_t)N_ * E_ * H_ * L_;               // n*R*L bf16

    k01<<<768 + N_ * E_ * H_, 256, 0, stream>>>(seq, att, mpos, mmask, seqT, e_emb, e_att);
    k2_pairs<<<N_ * R_, 256, 0, stream>>>(hts, e_emb, e_att, ht, out);
    dim3 g3(D_ / 32, R_ / 32, N_);
    k3_rs<<<g3, 64, 0, stream>>>(seqT, ht, out + (size_t)2 * N_ * R_ * D_);
}